// Round 4
// baseline (90.360 us; speedup 1.0000x reference)
//
#include <hip/hip_runtime.h>

// RoI bilinear crop-and-resize (TF2 half-pixel-center resize semantics).
// image: (1, 128, 128, 1024) f32, rois: (256, 4) f32 [x, y, w, h]
// out:   (1, 256, 14, 14, 1024) f32
//
// R4: one block per output ROW (n, yj) -> 3584 blocks; each thread owns 4
// channels and loops the 14 xj pixels (unroll 4 for load ILP). Amortizes
// geometry, pipelines loads (was latency-bound at 1 load-round per block).
// NT output stores (keep image in L3) + bijective XCD swizzle retained.

#define H_ 128
#define W_ 128
#define C_ 1024
#define POOL_ 14
#define NROI_ 256
#define NBLK_ (NROI_ * POOL_)   // 3584, divisible by 8
#define NXCD_ 8

typedef float f32x4 __attribute__((ext_vector_type(4)));

__global__ __launch_bounds__(256) void roi_pool_row_kernel(
    const float* __restrict__ feat,   // (H, W, C)
    const float* __restrict__ rois,   // (N, 4)
    float* __restrict__ out)          // (N, 14, 14, C)
{
    // Bijective XCD swizzle: XCD k gets contiguous rows [k*448, (k+1)*448)
    // == RoIs [k*32, (k+1)*32) -> per-RoI source footprint lives in one L2.
    const int bid = blockIdx.x;
    const int blk = (bid % NXCD_) * (NBLK_ / NXCD_) + bid / NXCD_;

    const int yj = blk % POOL_;
    const int n  = blk / POOL_;

    // Per-RoI geometry (wave-uniform; ~40 flops once per block).
    const float x = rois[n * 4 + 0];
    const float y = rois[n * 4 + 1];
    const float w = rois[n * 4 + 2];
    const float h = rois[n * 4 + 3];

    // jnp.round == round-half-to-even == rintf
    const int r  = (int)rintf((x - w * 0.5f) / 16.0f);
    const int c  = (int)rintf((y - h * 0.5f) / 16.0f);
    const int wf = max((int)rintf(w / 16.0f), 1);
    const int hf = max((int)rintf(h / 16.0f), 1);

    // y axis (rows): start=c, size=hf, limit=H   -- once per block
    const float scy  = (float)hf / (float)POOL_;
    const float srcy = ((float)yj + 0.5f) * scy - 0.5f;
    const float fly  = floorf(srcy);
    const float ty   = srcy - fly;                 // unclamped lerp weight
    const float hiy  = (float)(hf - 1);
    int y0 = (int)fminf(fmaxf(fly, 0.0f), hiy) + c;
    int y1 = (int)fminf(fmaxf(fly + 1.0f, 0.0f), hiy) + c;
    y0 = min(max(y0, 0), H_ - 1);
    y1 = min(max(y1, 0), H_ - 1);

    const float omty = 1.0f - ty;

    const float* __restrict__ row0 = feat + (size_t)y0 * W_ * C_;
    const float* __restrict__ row1 = feat + (size_t)y1 * W_ * C_;
    float* __restrict__ orow = out + ((size_t)n * (POOL_ * POOL_) + (size_t)yj * POOL_) * C_;

    const int tid = threadIdx.x;              // 0..255 -> channel group
    const int ch4 = tid;                      // float4 index within C

    const float scx = (float)wf / (float)POOL_;
    const float hix = (float)(wf - 1);

    #pragma unroll 4
    for (int xj = 0; xj < POOL_; ++xj) {
        // x axis (cols): start=r, size=wf, limit=W
        const float srcx = ((float)xj + 0.5f) * scx - 0.5f;
        const float flx  = floorf(srcx);
        const float tx   = srcx - flx;
        int x0 = (int)fminf(fmaxf(flx, 0.0f), hix) + r;
        int x1 = (int)fminf(fmaxf(flx + 1.0f, 0.0f), hix) + r;
        x0 = min(max(x0, 0), W_ - 1);
        x1 = min(max(x1, 0), W_ - 1);

        const f32x4 v00 = ((const f32x4*)(row0 + (size_t)x0 * C_))[ch4];
        const f32x4 v01 = ((const f32x4*)(row0 + (size_t)x1 * C_))[ch4];
        const f32x4 v10 = ((const f32x4*)(row1 + (size_t)x0 * C_))[ch4];
        const f32x4 v11 = ((const f32x4*)(row1 + (size_t)x1 * C_))[ch4];

        const float omtx = 1.0f - tx;

        // Match reference order:
        // (v00*(1-ty) + v10*ty)*(1-tx) + (v01*(1-ty) + v11*ty)*tx
        f32x4 o = (v00 * omty + v10 * ty) * omtx + (v01 * omty + v11 * ty) * tx;

        // Non-temporal: stream output past L2/L3 so the image stays cached.
        __builtin_nontemporal_store(o, (f32x4*)(orow + (size_t)xj * C_) + ch4);
    }
}

extern "C" void kernel_launch(void* const* d_in, const int* in_sizes, int n_in,
                              void* d_out, int out_size, void* d_ws, size_t ws_size,
                              hipStream_t stream) {
    const float* feat = (const float*)d_in[0];   // (1,128,128,1024) f32
    const float* rois = (const float*)d_in[1];   // (256,4) f32
    float* out = (float*)d_out;                  // (1,256,14,14,1024) f32

    roi_pool_row_kernel<<<NBLK_, 256, 0, stream>>>(feat, rois, out);
}